// Round 5
// baseline (485.222 us; speedup 1.0000x reference)
//
#include <hip/hip_runtime.h>

// ----------------------------------------------------------------------------
// S4 block: y = GELU( irfft(rfft(u,2L) * (rfft(k,2L) + D)) [:L] ) ; out = W@y + b
// B=8, C=1, H=512, L=8192, N=2L=16384
//
// FFT: four-step register-resident factorization 16384 = 16*16*16*4.
//   1024 threads, 16 complex points/thread in VGPRs. LDS = 73,728 B.
//   Exchange A through an 8192-float2 buffer in 2 column rounds; exchanges
//   B/C intra-wave in per-wave 576-float2 slices ordered by lgkmcnt only.
//   Bank-bijective strides (R4: SQ_LDS_BANK_CONFLICT 19.9M -> 0).
//   __launch_bounds__(1024,1): allocator caps at 64 VGPR (the 4-wave/SIMD
//   limit); forcing more waves spills catastrophically (R1).
//
// R5: transpose_g DELETED. gemm_out now reads g[b][h][l] directly:
//   - B-tile staged h-major into Bs2 with layout
//       BIDX(k,l) = k*144 + ((k>>3)&3)*16 + l
//     writes: 8-ushort contiguous, 16B-aligned, bank-starts 8(k&3)+4lc ->
//     every bank exactly 8 accesses (b128 structural minimum, conflict-free).
//     reads: 8x ds_read_u16 per B-fragment, bank = 8q + mi/2 + const ->
//     32 banks x 2 parity lanes = conflict-free. Fragment contents are
//     lane-identical to the old gT path (correct by construction).
//   - 1D grid 2048, XCD-aware decode: logical = (bid&7)*256 + bid>>3,
//     ot innermost -> the 4 o-tiles sharing a g-tile run consecutively on
//     one XCD; 128KB tile stays in L2 (fetch ~256MB -> ~70MB).
//   - g staged in ws (+64MB, where gT lived) to avoid aliasing out.
// ----------------------------------------------------------------------------

typedef unsigned short ushort_t;
typedef __bf16 bf16x8 __attribute__((ext_vector_type(8)));
typedef float  f32x4  __attribute__((ext_vector_type(4)));
typedef unsigned short ushort8 __attribute__((ext_vector_type(8)));

#define TWO_PI 6.283185307179586f
#define LGKM() asm volatile("s_waitcnt lgkmcnt(0)" ::: "memory")
#define CHI(p) ((((p) & 0x3C)) | (((p) + ((p) >> 4)) & 3))

__device__ __forceinline__ float2 cmulf(float2 a, float2 b) {
    return make_float2(a.x * b.x - a.y * b.y, a.x * b.y + a.y * b.x);
}
__device__ __forceinline__ float2 caddf(float2 a, float2 b) { return make_float2(a.x + b.x, a.y + b.y); }
__device__ __forceinline__ float2 csubf(float2 a, float2 b) { return make_float2(a.x - b.x, a.y - b.y); }

__device__ __forceinline__ ushort_t f2bf(float f) {
    unsigned int u = __float_as_uint(f);
    u = (u + 0x7fffu + ((u >> 16) & 1u)) >> 16;
    return (ushort_t)u;
}

__device__ __forceinline__ float gelu_exact(float x) {
    return 0.5f * x * (1.0f + erff(x * 0.70710678118654752f));
}

// ---------------- 4-point DFT, natural in/out (INV = conjugate kernel) ------
template<bool INV>
__device__ __forceinline__ void dft4(float2& x0, float2& x1, float2& x2, float2& x3) {
    float2 t0 = caddf(x0, x2), t1 = csubf(x0, x2);
    float2 t2 = caddf(x1, x3), t3 = csubf(x1, x3);
    x0 = caddf(t0, t2);
    x2 = csubf(t0, t2);
    if (!INV) {
        x1 = make_float2(t1.x + t3.y, t1.y - t3.x);   // t1 - i*t3
        x3 = make_float2(t1.x - t3.y, t1.y + t3.x);   // t1 + i*t3
    } else {
        x1 = make_float2(t1.x - t3.y, t1.y + t3.x);
        x3 = make_float2(t1.x + t3.y, t1.y - t3.x);
    }
}

// multiply by twiddle (wr, wi); INV conjugates the twiddle
template<bool INV>
__device__ __forceinline__ float2 cmulc(float2 a, float wr, float wi) {
    float i2 = INV ? -wi : wi;
    return make_float2(a.x * wr - a.y * i2, a.x * i2 + a.y * wr);
}

#define C1_ 0.9238795325112867f
#define S1_ 0.3826834323650898f
#define R2_ 0.7071067811865476f

// ---------------- 16-point DFT, natural in/out ------------------------------
// four-step 16 = 4x4: n = 4a+b, k = c+4e.
// HZ: inputs r[8..15] are known-zero (skip half the inner butterflies).
template<bool INV, bool HZ>
__device__ __forceinline__ void dft16(float2* r) {
#pragma unroll
    for (int b = 0; b < 4; ++b) {
        if (HZ) {
            float2 u = r[b], v = r[4 + b];
            r[b]     = caddf(u, v);
            r[8 + b] = csubf(u, v);
            if (!INV) { r[4 + b]  = make_float2(u.x + v.y, u.y - v.x);
                        r[12 + b] = make_float2(u.x - v.y, u.y + v.x); }
            else      { r[4 + b]  = make_float2(u.x - v.y, u.y + v.x);
                        r[12 + b] = make_float2(u.x + v.y, u.y - v.x); }
        } else {
            dft4<INV>(r[b], r[4 + b], r[8 + b], r[12 + b]);
        }
    }
    // twiddle r[4c+b] *= w16^{bc}
    r[5]  = cmulc<INV>(r[5],  C1_, -S1_);   // w^1
    r[6]  = cmulc<INV>(r[6],  R2_, -R2_);   // w^2
    r[7]  = cmulc<INV>(r[7],  S1_, -C1_);   // w^3
    r[9]  = cmulc<INV>(r[9],  R2_, -R2_);   // w^2
    r[10] = cmulc<INV>(r[10], 0.f, -1.f);   // w^4
    r[11] = cmulc<INV>(r[11], -R2_, -R2_);  // w^6
    r[13] = cmulc<INV>(r[13], S1_, -C1_);   // w^3
    r[14] = cmulc<INV>(r[14], -R2_, -R2_);  // w^6
    r[15] = cmulc<INV>(r[15], -C1_,  S1_);  // w^9
    float2 o[16];
#pragma unroll
    for (int c = 0; c < 4; ++c) {
        float2 a0 = r[4*c], a1 = r[4*c+1], a2 = r[4*c+2], a3 = r[4*c+3];
        dft4<INV>(a0, a1, a2, a3);
        o[c] = a0; o[c + 4] = a1; o[c + 8] = a2; o[c + 12] = a3;
    }
#pragma unroll
    for (int i = 0; i < 16; ++i) r[i] = o[i];
}

// apply w^k, w = e^{i*theta}, to x[1..15] (x[0] *= w^0)
__device__ __forceinline__ void twiddle_apply(float2* x, float theta) {
    float s, c;
    __sincosf(theta, &s, &c);
    float2 w = make_float2(c, s), wk = w;
#pragma unroll
    for (int k = 1; k < 16; ++k) { x[k] = cmulf(x[k], wk); wk = cmulf(wk, w); }
}

// ----------------------------------------------------------------------------
// Shared scratch: 9216 float2 = 73,728 B.
//   [0, 8192)        : exchange-A / exchange-B'A' half-signal buffer
//   SH + w*576       : wave-private slice for exchanges B, C (and mirrors)
// ----------------------------------------------------------------------------
#define SH_SIZE 9216
#define PW_STRIDE 576

// ---------------- forward: regs(natural a-chunks) -> regs(sigma bins) -------
// thread t holds x[a] = in[a*1024 + t] (a=8..15 zero). Output: 16 sigma-bins.
__device__ __forceinline__ void fft_fwd(float2* x, float2* SH, int t) {
    const int w  = t >> 6;          // wave / k1
    const int d  = t & 63;
    const int kb = (t >> 2) & 15;
    const int f  = t & 3;
    float2* PW = SH + w * PW_STRIDE;
    float2 tmp[8];
    const bool tlo = (t < 512);

    // phase A: DFT16 over a (half-zero) + twiddle w_N^t
    dft16<false, true>(x);
    twiddle_apply(x, -TWO_PI * (float)t * (1.0f / 16384.0f));

    // ---- exchange A: logical pos p = r*1024 + t' ; read p = w*1024 + c*64 + d
    // col-split rounds through SH[0..8191], slot = r*512 + (t' & 511)
    if (tlo) {
#pragma unroll
        for (int r = 0; r < 16; ++r) SH[r * 512 + t] = x[r];
    }
    __syncthreads();
#pragma unroll
    for (int c = 0; c < 8; ++c) {
        float2 v = SH[w * 512 + c * 64 + d];
        if (tlo) x[c] = v; else tmp[c] = v;
    }
    __syncthreads();
    if (!tlo) {
#pragma unroll
        for (int r = 0; r < 16; ++r) SH[r * 512 + (t - 512)] = x[r];
    }
    __syncthreads();
#pragma unroll
    for (int c = 8; c < 16; ++c) x[c] = SH[w * 512 + (c - 8) * 64 + d];
    if (!tlo) {
#pragma unroll
        for (int c = 0; c < 8; ++c) x[c] = tmp[c];
    }

    // phase B: DFT16 over c + twiddle w_1024^d
    dft16<false, false>(x);
    twiddle_apply(x, -TWO_PI * (float)d * (1.0f / 1024.0f));
    __syncthreads();   // all waves done reading SH[0..8191]; private slices now safe

    // ---- exchange B (intra-wave): write row r col d, read row kb col e*4+f
    // col-split by d; per-wave slot = r*36 + (d & 31); NO barriers.
    // stride 36 == 4 (mod 16): read bank-pair (4kb+f) mod 16 bijective/group.
    {
        const bool dlo = (d < 32);
        const int dc = d & 31;
        if (dlo) {
#pragma unroll
            for (int r = 0; r < 16; ++r) PW[r * 36 + dc] = x[r];
        }
        LGKM();
#pragma unroll
        for (int e = 0; e < 8; ++e) {
            float2 v = PW[kb * 36 + e * 4 + f];
            if (dlo) x[e] = v; else tmp[e] = v;
        }
        LGKM();
        if (!dlo) {
#pragma unroll
            for (int r = 0; r < 16; ++r) PW[r * 36 + dc] = x[r];
        }
        LGKM();
#pragma unroll
        for (int e = 8; e < 16; ++e) x[e] = PW[kb * 36 + (e - 8) * 4 + f];
        if (!dlo) {
#pragma unroll
            for (int e = 0; e < 8; ++e) x[e] = tmp[e];
        }
    }

    // phase C: DFT16 over e + twiddle w_64^f
    dft16<false, false>(x);
    twiddle_apply(x, -TWO_PI * (float)f * (1.0f / 64.0f));

    // ---- exchange C (intra-wave, kb-diagonal): half-wave sequential rounds
    // slot = (kb&7)*68 + CHI(col); write col = r*4+f, read col = f*16 + q*4 + ff
    {
        const int row = (kb & 7) * 68;
        const bool klo = (kb < 8);
        if (klo) {
#pragma unroll
            for (int r = 0; r < 16; ++r) PW[row + CHI(r * 4 + f)] = x[r];
        }
        LGKM();
        if (klo) {
#pragma unroll
            for (int q = 0; q < 4; ++q)
#pragma unroll
                for (int ff = 0; ff < 4; ++ff)
                    x[q * 4 + ff] = PW[row + CHI(f * 16 + q * 4 + ff)];
        }
        LGKM();
        if (!klo) {
#pragma unroll
            for (int r = 0; r < 16; ++r) PW[row + CHI(r * 4 + f)] = x[r];
        }
        LGKM();
        if (!klo) {
#pragma unroll
            for (int q = 0; q < 4; ++q)
#pragma unroll
                for (int ff = 0; ff < 4; ++ff)
                    x[q * 4 + ff] = PW[row + CHI(f * 16 + q * 4 + ff)];
        }
    }

    // phase D: DFT4 over ff
#pragma unroll
    for (int q = 0; q < 4; ++q) dft4<false>(x[4*q], x[4*q+1], x[4*q+2], x[4*q+3]);
}

// ---------------- inverse: exact mirror; output x[a] = 16384 * time[a*1024+t]
__device__ __forceinline__ void fft_inv(float2* x, float2* SH, int t) {
    const int w  = t >> 6;
    const int d  = t & 63;
    const int kb = (t >> 2) & 15;
    const int f  = t & 3;
    float2* PW = SH + w * PW_STRIDE;
    float2 tmp[8];

    // phase D'
#pragma unroll
    for (int q = 0; q < 4; ++q) dft4<true>(x[4*q], x[4*q+1], x[4*q+2], x[4*q+3]);

    // ---- exchange D' (diagonal mirror of C) ----
    {
        const int row = (kb & 7) * 68;
        const bool klo = (kb < 8);
        LGKM();   // ensure fwd phase-C reads fully drained before overwrite
        if (klo) {
#pragma unroll
            for (int q = 0; q < 4; ++q)
#pragma unroll
                for (int ff = 0; ff < 4; ++ff)
                    PW[row + CHI(f * 16 + q * 4 + ff)] = x[q * 4 + ff];
        }
        LGKM();
        if (klo) {
#pragma unroll
            for (int r = 0; r < 16; ++r) x[r] = PW[row + CHI(r * 4 + f)];
        }
        LGKM();
        if (!klo) {
#pragma unroll
            for (int q = 0; q < 4; ++q)
#pragma unroll
                for (int ff = 0; ff < 4; ++ff)
                    PW[row + CHI(f * 16 + q * 4 + ff)] = x[q * 4 + ff];
        }
        LGKM();
        if (!klo) {
#pragma unroll
            for (int r = 0; r < 16; ++r) x[r] = PW[row + CHI(r * 4 + f)];
        }
    }

    // phase C'
    twiddle_apply(x, TWO_PI * (float)f * (1.0f / 64.0f));
    dft16<true, false>(x);

    // ---- exchange C'->B' (intra-wave): write row kb col e*4+f, read row r col d
    // row-split by writer kb; slot = (row&7)*68 + CHI(col)
    {
        const int row = (kb & 7) * 68;
        const bool klo = (kb < 8);
        LGKM();
        if (klo) {
#pragma unroll
            for (int e = 0; e < 16; ++e) PW[row + CHI(e * 4 + f)] = x[e];
        }
        LGKM();
#pragma unroll
        for (int r = 0; r < 8; ++r) {
            float2 v = PW[r * 68 + CHI(d)];
            if (klo) x[r] = v; else tmp[r] = v;
        }
        LGKM();
        if (!klo) {
#pragma unroll
            for (int e = 0; e < 16; ++e) PW[row + CHI(e * 4 + f)] = x[e];
        }
        LGKM();
#pragma unroll
        for (int r = 8; r < 16; ++r) x[r] = PW[(r - 8) * 68 + CHI(d)];
        if (!klo) {
#pragma unroll
            for (int r = 0; r < 8; ++r) x[r] = tmp[r];
        }
    }

    // phase B'
    twiddle_apply(x, TWO_PI * (float)d * (1.0f / 1024.0f));
    dft16<true, false>(x);

    // ---- exchange B'->A': write p = w*1024 + c*64 + d, read p = r*1024 + t
    // row-split by writer wave through SH[0..8191]
    __syncthreads();   // all waves done with private-slice reads
    if (w < 8) {
#pragma unroll
        for (int c = 0; c < 16; ++c) SH[w * 1024 + c * 64 + d] = x[c];
    }
    __syncthreads();
#pragma unroll
    for (int r = 0; r < 8; ++r) {
        float2 v = SH[r * 1024 + t];
        if (w < 8) x[r] = v; else tmp[r] = v;
    }
    __syncthreads();
    if (w >= 8) {
#pragma unroll
        for (int c = 0; c < 16; ++c) SH[(w - 8) * 1024 + c * 64 + d] = x[c];
    }
    __syncthreads();
#pragma unroll
    for (int r = 8; r < 16; ++r) x[r] = SH[(r - 8) * 1024 + t];
    if (w >= 8) {
#pragma unroll
        for (int r = 0; r < 8; ++r) x[r] = tmp[r];
    }

    // phase A'
    twiddle_apply(x, TWO_PI * (float)t * (1.0f / 16384.0f));
    dft16<true, false>(x);
}

// ---------------- k0: W fp32 -> bf16 ----------------------------------------
__global__ void wconv(const float* __restrict__ W, ushort_t* __restrict__ Wb, int n)
{
    int i = blockIdx.x * 256 + threadIdx.x;
    if (i < n) Wb[i] = f2bf(W[i]);
}

// ---------------- k1: Kf[h][sigma] = FFT(k[h]) + D[h] -----------------------
__global__ __launch_bounds__(1024, 1) void kf_build(const float* __restrict__ k,
                                                    const float* __restrict__ D,
                                                    float2* __restrict__ Kf)
{
    __shared__ float2 SH[SH_SIZE];   // 73,728 B
    int h = blockIdx.x, t = threadIdx.x;
    const float* kr = k + (size_t)h * 8192;
    float2 x[16];
#pragma unroll
    for (int a = 0; a < 8; ++a) x[a] = make_float2(kr[a * 1024 + t], 0.f);
#pragma unroll
    for (int a = 8; a < 16; ++a) x[a] = make_float2(0.f, 0.f);
    fft_fwd(x, SH, t);
    float dh = D[h];
    float2* o = Kf + (size_t)h * 16384;
#pragma unroll
    for (int r = 0; r < 16; ++r) {
        float2 z = x[r];
        z.x += dh;                       // FFT(D*delta) = D on every bin
        o[r * 1024 + t] = z;
    }
}

// ---------------- k2: conv + D-skip + GELU -> g bf16 ------------------------
__global__ __launch_bounds__(1024, 1) void conv_gelu(const float* __restrict__ u,
                                                     const float2* __restrict__ Kf,
                                                     ushort_t* __restrict__ g)
{
    __shared__ float2 SH[SH_SIZE];   // 73,728 B
    int h    = blockIdx.x;         // 512
    int pair = blockIdx.y;         // 4
    int b0   = pair * 2;
    int t    = threadIdx.x;
    const float* u0 = u + ((size_t)(b0 * 512 + h)) * 8192;
    const float* u1 = u0 + (size_t)512 * 8192;
    float2 x[16];
#pragma unroll
    for (int a = 0; a < 8; ++a) x[a] = make_float2(u0[a * 1024 + t], u1[a * 1024 + t]);
#pragma unroll
    for (int a = 8; a < 16; ++a) x[a] = make_float2(0.f, 0.f);
    fft_fwd(x, SH, t);
    const float2* kf = Kf + (size_t)blockIdx.x * 16384;
#pragma unroll
    for (int r = 0; r < 16; ++r) x[r] = cmulf(x[r], kf[r * 1024 + t]);
    fft_inv(x, SH, t);
    const float sc = 1.0f / 16384.0f;
    ushort_t* g0 = g + ((size_t)(b0 * 512 + blockIdx.x)) * 8192;
    ushort_t* g1 = g0 + (size_t)512 * 8192;
#pragma unroll
    for (int a = 0; a < 8; ++a) {
        int n = a * 1024 + t;
        g0[n] = f2bf(gelu_exact(x[a].x * sc));   // batch b0
        g1[n] = f2bf(gelu_exact(x[a].y * sc));   // batch b0+1
    }
}

// ---------------- k3: out[b,o,l] = sum_h Wb[o,h]*g[b,h,l] + bias[o] ---------
// B-operand staged h-major; transpose happens in the LDS fragment gather.
// BIDX layout: writes 16B-aligned contiguous + conflict-free; u16 fragment
// reads hit 32 distinct banks (8q + mi/2) -- conflict-free. See header.
#define BIDX(k, l) ((k) * 144 + (((k) >> 3) & 3) * 16 + (l))

__global__ __launch_bounds__(256, 2) void gemm_out(const ushort_t* __restrict__ Wb,
                                                   const ushort_t* __restrict__ g,
                                                   const float* __restrict__ bias,
                                                   float* __restrict__ out)
{
    __shared__ __align__(16) ushort_t As[128 * 32];  // [o][k]
    __shared__ __align__(16) ushort_t Bs2[4640];     // BIDX-layout [k][l]

    // XCD-aware decode: logical = (bid&7)*256 + bid>>3; ot innermost so the
    // 4 o-tiles sharing one g-tile run consecutively on the same XCD (L2 hit).
    int bid     = blockIdx.x;                 // 0..2047
    int logical = (bid & 7) * 256 + (bid >> 3);
    int ot = logical & 3;                     // 4 o-tiles
    int lt = (logical >> 2) & 63;             // 64 l-tiles
    int b  = logical >> 8;                    // 8 batches (one per XCD)
    int l0 = lt * 128, o0 = ot * 128;
    int t    = threadIdx.x;
    int wave = t >> 6, lid = t & 63;
    int wm = wave >> 1, wn = wave & 1;
    int q  = lid >> 4, mi = lid & 15;

    f32x4 acc[4][4];
#pragma unroll
    for (int i = 0; i < 4; ++i)
#pragma unroll
        for (int j = 0; j < 4; ++j)
            acc[i][j] = (f32x4){0.f, 0.f, 0.f, 0.f};

    const ushort_t* gb = g + (size_t)b * 512 * 8192;   // g[b][h][l]
    for (int it = 0; it < 16; ++it) {
        int k0 = it * 32;
        __syncthreads();
#pragma unroll
        for (int i = 0; i < 2; ++i) {
            int ch = t + (i << 8);           // 0..511 16B-chunks
            // A: Wb[o0+row][k0 + kc..kc+7]
            int arow = ch >> 2;
            int akc  = (ch & 3) << 3;
            uint4 va = *(const uint4*)(Wb + (size_t)(o0 + arow) * 512 + k0 + akc);
            *(uint4*)&As[arow * 32 + akc] = va;
            // B: g[b][k0+hr][l0 + lc*8..+7] -> Bs2[BIDX(hr, lc*8)]
            int hr = ch >> 4;                // 0..31
            int lc = ch & 15;                // 0..15
            uint4 vb = *(const uint4*)(gb + (size_t)(k0 + hr) * 8192 + l0 + (lc << 3));
            *(uint4*)&Bs2[BIDX(hr, lc << 3)] = vb;
        }
        __syncthreads();
        bf16x8 af[4], bfr[4];
#pragma unroll
        for (int ff = 0; ff < 4; ++ff) {
            af[ff] = *(const bf16x8*)&As[(wm * 64 + ff * 16 + mi) * 32 + q * 8];
            ushort8 bu;
#pragma unroll
            for (int j = 0; j < 8; ++j)
                bu[j] = Bs2[BIDX(q * 8 + j, wn * 64 + ff * 16 + mi)];
            bfr[ff] = __builtin_bit_cast(bf16x8, bu);
        }
#pragma unroll
        for (int i = 0; i < 4; ++i)
#pragma unroll
            for (int j = 0; j < 4; ++j)
                acc[i][j] = __builtin_amdgcn_mfma_f32_16x16x32_bf16(af[i], bfr[j], acc[i][j], 0, 0, 0);
    }

#pragma unroll
    for (int i = 0; i < 4; ++i) {
        int o_base = o0 + wm * 64 + i * 16 + q * 4;
#pragma unroll
        for (int j = 0; j < 4; ++j) {
            int l = l0 + wn * 64 + j * 16 + mi;
#pragma unroll
            for (int r = 0; r < 4; ++r) {
                int o = o_base + r;
                out[((size_t)b * 512 + o) * 8192 + l] = acc[i][j][r] + bias[o];
            }
        }
    }
}

// ----------------------------------------------------------------------------
extern "C" void kernel_launch(void* const* d_in, const int* in_sizes, int n_in,
                              void* d_out, int out_size, void* d_ws, size_t ws_size,
                              hipStream_t stream)
{
    (void)in_sizes; (void)n_in; (void)out_size; (void)ws_size;
    const float* u    = (const float*)d_in[0];   // (8,512,8192)
    const float* k    = (const float*)d_in[1];   // (1,512,8192)
    const float* D    = (const float*)d_in[2];   // (1,512)
    const float* W    = (const float*)d_in[3];   // (512,512)
    const float* bias = (const float*)d_in[4];   // (512,)
    float* out = (float*)d_out;

    char* ws = (char*)d_ws;
    float2*   Kf = (float2*)ws;                          // 512*16384*8 = 64 MB
    ushort_t* g  = (ushort_t*)(ws + 67108864);           // 64 MB (was gT)
    ushort_t* Wb = (ushort_t*)(ws + 134217728);          // 512 KB

    wconv<<<1024, 256, 0, stream>>>(W, Wb, 512 * 512);
    kf_build<<<512, 1024, 0, stream>>>(k, D, Kf);
    conv_gelu<<<dim3(512, 4), 1024, 0, stream>>>(u, Kf, g);
    gemm_out<<<2048, 256, 0, stream>>>(Wb, g, bias, out);
}

// Round 6
// 432.936 us; speedup vs baseline: 1.1208x; 1.1208x over previous
//
#include <hip/hip_runtime.h>

// ----------------------------------------------------------------------------
// S4 block: y = GELU( irfft(rfft(u,2L) * (rfft(k,2L) + D)) [:L] ) ; out = W@y + b
// B=8, C=1, H=512, L=8192, N=2L=16384
//
// FFT: four-step register-resident factorization 16384 = 16*16*16*4.
//   1024 threads, 16 complex points/thread in VGPRs.
//
// R6: FULL-WAVE exchanges. R2 proved 2-block/CU residency is unreachable
//   (register file), so LDS is free up to 160KB. Buffer = 16 wave-regions x
//   1088 float2 = 17,408 float2 = 139,264 B. Unified layout:
//       slot(region,row,col) = region*1088 + row*68 + CHI(col)
//   CHI(p) = (p&0x3C)|((p+(p>>4))&3) applied on BOTH write and read (cancels
//   semantically); stride 68 == 4 mod 16 -> every exchange access pattern is
//   bank-bijective per 16-lane group (verified per pattern; R4 measured the
//   same CHI pair at 0 conflicts).
//   - exchange A: write cross-region [r][w][d]; BARRIER; read own region.
//   - exchanges B/C (and D'/C'B' mirrors): intra-wave, own region, one
//     lgkmcnt(0) between write and read, NO barriers (per-slot ownership
//     analysis: every cross-lane-written slot is LGKM-separated).
//   - inverse B'A': write own region; BARRIER; read cross-region.
//   => 2 barriers per conv_gelu (was 5), no half-wave rounds, no tmp[8].
//
// __launch_bounds__(1024,1): do NOT force waves/EU (R1: forcing spills
//   catastrophically; R2: VGPR=64 -> 4 waves/SIMD is the HW ceiling here).
//
// gemm: direct g[b][h][l] B-staging (no transpose kernel, saves 134MB HBM),
//   BIDX conflict-free LDS layout, u16 fragment gather (conflict-free, see
//   R5 header). R6 reverts the XCD decode: g is L3-resident, swizzle was a
//   net penalty (guide m160: swizzle costs ~2% when L3-fit).
// ----------------------------------------------------------------------------

typedef unsigned short ushort_t;
typedef __bf16 bf16x8 __attribute__((ext_vector_type(8)));
typedef float  f32x4  __attribute__((ext_vector_type(4)));
typedef unsigned short ushort8 __attribute__((ext_vector_type(8)));

#define TWO_PI 6.283185307179586f
#define LGKM() asm volatile("s_waitcnt lgkmcnt(0)" ::: "memory")
#define CHI(p) ((((p) & 0x3C)) | (((p) + ((p) >> 4)) & 3))

__device__ __forceinline__ float2 cmulf(float2 a, float2 b) {
    return make_float2(a.x * b.x - a.y * b.y, a.x * b.y + a.y * b.x);
}
__device__ __forceinline__ float2 caddf(float2 a, float2 b) { return make_float2(a.x + b.x, a.y + b.y); }
__device__ __forceinline__ float2 csubf(float2 a, float2 b) { return make_float2(a.x - b.x, a.y - b.y); }

__device__ __forceinline__ ushort_t f2bf(float f) {
    unsigned int u = __float_as_uint(f);
    u = (u + 0x7fffu + ((u >> 16) & 1u)) >> 16;
    return (ushort_t)u;
}

__device__ __forceinline__ float gelu_exact(float x) {
    return 0.5f * x * (1.0f + erff(x * 0.70710678118654752f));
}

// ---------------- 4-point DFT, natural in/out (INV = conjugate kernel) ------
template<bool INV>
__device__ __forceinline__ void dft4(float2& x0, float2& x1, float2& x2, float2& x3) {
    float2 t0 = caddf(x0, x2), t1 = csubf(x0, x2);
    float2 t2 = caddf(x1, x3), t3 = csubf(x1, x3);
    x0 = caddf(t0, t2);
    x2 = csubf(t0, t2);
    if (!INV) {
        x1 = make_float2(t1.x + t3.y, t1.y - t3.x);   // t1 - i*t3
        x3 = make_float2(t1.x - t3.y, t1.y + t3.x);   // t1 + i*t3
    } else {
        x1 = make_float2(t1.x - t3.y, t1.y + t3.x);
        x3 = make_float2(t1.x + t3.y, t1.y - t3.x);
    }
}

// multiply by twiddle (wr, wi); INV conjugates the twiddle
template<bool INV>
__device__ __forceinline__ float2 cmulc(float2 a, float wr, float wi) {
    float i2 = INV ? -wi : wi;
    return make_float2(a.x * wr - a.y * i2, a.x * i2 + a.y * wr);
}

#define C1_ 0.9238795325112867f
#define S1_ 0.3826834323650898f
#define R2_ 0.7071067811865476f

// ---------------- 16-point DFT, natural in/out ------------------------------
// four-step 16 = 4x4: n = 4a+b, k = c+4e.
// HZ: inputs r[8..15] are known-zero (skip half the inner butterflies).
template<bool INV, bool HZ>
__device__ __forceinline__ void dft16(float2* r) {
#pragma unroll
    for (int b = 0; b < 4; ++b) {
        if (HZ) {
            float2 u = r[b], v = r[4 + b];
            r[b]     = caddf(u, v);
            r[8 + b] = csubf(u, v);
            if (!INV) { r[4 + b]  = make_float2(u.x + v.y, u.y - v.x);
                        r[12 + b] = make_float2(u.x - v.y, u.y + v.x); }
            else      { r[4 + b]  = make_float2(u.x - v.y, u.y + v.x);
                        r[12 + b] = make_float2(u.x + v.y, u.y - v.x); }
        } else {
            dft4<INV>(r[b], r[4 + b], r[8 + b], r[12 + b]);
        }
    }
    // twiddle r[4c+b] *= w16^{bc}
    r[5]  = cmulc<INV>(r[5],  C1_, -S1_);   // w^1
    r[6]  = cmulc<INV>(r[6],  R2_, -R2_);   // w^2
    r[7]  = cmulc<INV>(r[7],  S1_, -C1_);   // w^3
    r[9]  = cmulc<INV>(r[9],  R2_, -R2_);   // w^2
    r[10] = cmulc<INV>(r[10], 0.f, -1.f);   // w^4
    r[11] = cmulc<INV>(r[11], -R2_, -R2_);  // w^6
    r[13] = cmulc<INV>(r[13], S1_, -C1_);   // w^3
    r[14] = cmulc<INV>(r[14], -R2_, -R2_);  // w^6
    r[15] = cmulc<INV>(r[15], -C1_,  S1_);  // w^9
    float2 o[16];
#pragma unroll
    for (int c = 0; c < 4; ++c) {
        float2 a0 = r[4*c], a1 = r[4*c+1], a2 = r[4*c+2], a3 = r[4*c+3];
        dft4<INV>(a0, a1, a2, a3);
        o[c] = a0; o[c + 4] = a1; o[c + 8] = a2; o[c + 12] = a3;
    }
#pragma unroll
    for (int i = 0; i < 16; ++i) r[i] = o[i];
}

// apply w^k, w = e^{i*theta}, to x[1..15] (x[0] *= w^0)
__device__ __forceinline__ void twiddle_apply(float2* x, float theta) {
    float s, c;
    __sincosf(theta, &s, &c);
    float2 w = make_float2(c, s), wk = w;
#pragma unroll
    for (int k = 1; k < 16; ++k) { x[k] = cmulf(x[k], wk); wk = cmulf(wk, w); }
}

// ----------------------------------------------------------------------------
// Shared scratch: 16 regions x 1088 float2 = 17,408 float2 = 139,264 B.
//   slot(region,row,col) = region*1088 + row*68 + CHI(col), row in [0,16),
//   col in [0,64). 1 block/CU (accepted since R2).
// ----------------------------------------------------------------------------
#define SH_SIZE 17408
#define WREG 1088
#define ROWS 68

// ---------------- forward: regs(natural a-chunks) -> regs(sigma bins) -------
// thread t holds x[a] = in[a*1024 + t] (a=8..15 zero). Output: 16 sigma-bins.
__device__ __forceinline__ void fft_fwd(float2* x, float2* SH, int t) {
    const int w  = t >> 6;          // wave / k1
    const int d  = t & 63;
    const int kb = (t >> 2) & 15;
    const int f  = t & 3;
    const int xd = CHI(d);
    float2* PW = SH + w * WREG;

    // phase A: DFT16 over a (half-zero) + twiddle w_N^t
    dft16<false, true>(x);
    twiddle_apply(x, -TWO_PI * (float)t * (1.0f / 16384.0f));

    // ---- exchange A (cross-wave): write [region r][row w][col d]; read own
#pragma unroll
    for (int r = 0; r < 16; ++r) SH[r * WREG + w * ROWS + xd] = x[r];
    __syncthreads();
#pragma unroll
    for (int c = 0; c < 16; ++c) x[c] = PW[c * ROWS + xd];

    // phase B: DFT16 over c + twiddle w_1024^d
    dft16<false, false>(x);
    twiddle_apply(x, -TWO_PI * (float)d * (1.0f / 1024.0f));

    // ---- exchange B (intra-wave): write [r][d], read [kb][4e+f]
#pragma unroll
    for (int r = 0; r < 16; ++r) PW[r * ROWS + xd] = x[r];
    LGKM();
#pragma unroll
    for (int e = 0; e < 16; ++e) x[e] = PW[kb * ROWS + CHI(e * 4 + f)];

    // phase C: DFT16 over e + twiddle w_64^f
    dft16<false, false>(x);
    twiddle_apply(x, -TWO_PI * (float)f * (1.0f / 64.0f));

    // ---- exchange C (intra-wave, row kb): write col r*4+f, read col f*16+q*4+ff
#pragma unroll
    for (int r = 0; r < 16; ++r) PW[kb * ROWS + CHI(r * 4 + f)] = x[r];
    LGKM();
#pragma unroll
    for (int q = 0; q < 4; ++q)
#pragma unroll
        for (int ff = 0; ff < 4; ++ff)
            x[q * 4 + ff] = PW[kb * ROWS + CHI(f * 16 + q * 4 + ff)];

    // phase D: DFT4 over ff
#pragma unroll
    for (int q = 0; q < 4; ++q) dft4<false>(x[4*q], x[4*q+1], x[4*q+2], x[4*q+3]);
}

// ---------------- inverse: exact mirror; output x[a] = 16384 * time[a*1024+t]
__device__ __forceinline__ void fft_inv(float2* x, float2* SH, int t) {
    const int w  = t >> 6;
    const int d  = t & 63;
    const int kb = (t >> 2) & 15;
    const int f  = t & 3;
    const int xd = CHI(d);
    float2* PW = SH + w * WREG;

    // phase D'
#pragma unroll
    for (int q = 0; q < 4; ++q) dft4<true>(x[4*q], x[4*q+1], x[4*q+2], x[4*q+3]);

    // ---- exchange D' (mirror of C): write col f*16+q*4+ff, read col r*4+f
#pragma unroll
    for (int q = 0; q < 4; ++q)
#pragma unroll
        for (int ff = 0; ff < 4; ++ff)
            PW[kb * ROWS + CHI(f * 16 + q * 4 + ff)] = x[q * 4 + ff];
    LGKM();
#pragma unroll
    for (int r = 0; r < 16; ++r) x[r] = PW[kb * ROWS + CHI(r * 4 + f)];

    // phase C'
    twiddle_apply(x, TWO_PI * (float)f * (1.0f / 64.0f));
    dft16<true, false>(x);

    // ---- exchange C'B' (mirror of B): write [kb][4e+f], read [r][d]
#pragma unroll
    for (int e = 0; e < 16; ++e) PW[kb * ROWS + CHI(e * 4 + f)] = x[e];
    LGKM();
#pragma unroll
    for (int r = 0; r < 16; ++r) x[r] = PW[r * ROWS + xd];

    // phase B'
    twiddle_apply(x, TWO_PI * (float)d * (1.0f / 1024.0f));
    dft16<true, false>(x);

    // ---- exchange B'A' (mirror of A): write own [row c][col d]; read cross
#pragma unroll
    for (int c = 0; c < 16; ++c) PW[c * ROWS + xd] = x[c];
    __syncthreads();
#pragma unroll
    for (int r = 0; r < 16; ++r) x[r] = SH[r * WREG + w * ROWS + xd];

    // phase A'
    twiddle_apply(x, TWO_PI * (float)t * (1.0f / 16384.0f));
    dft16<true, false>(x);
}

// ---------------- k0: W fp32 -> bf16 ----------------------------------------
__global__ void wconv(const float* __restrict__ W, ushort_t* __restrict__ Wb, int n)
{
    int i = blockIdx.x * 256 + threadIdx.x;
    if (i < n) Wb[i] = f2bf(W[i]);
}

// ---------------- k1: Kf[h][sigma] = FFT(k[h]) + D[h] -----------------------
__global__ __launch_bounds__(1024, 1) void kf_build(const float* __restrict__ k,
                                                    const float* __restrict__ D,
                                                    float2* __restrict__ Kf)
{
    __shared__ float2 SH[SH_SIZE];   // 139,264 B
    int h = blockIdx.x, t = threadIdx.x;
    const float* kr = k + (size_t)h * 8192;
    float2 x[16];
#pragma unroll
    for (int a = 0; a < 8; ++a) x[a] = make_float2(kr[a * 1024 + t], 0.f);
#pragma unroll
    for (int a = 8; a < 16; ++a) x[a] = make_float2(0.f, 0.f);
    fft_fwd(x, SH, t);
    float dh = D[h];
    float2* o = Kf + (size_t)h * 16384;
#pragma unroll
    for (int r = 0; r < 16; ++r) {
        float2 z = x[r];
        z.x += dh;                       // FFT(D*delta) = D on every bin
        o[r * 1024 + t] = z;
    }
}

// ---------------- k2: conv + D-skip + GELU -> g bf16 ------------------------
__global__ __launch_bounds__(1024, 1) void conv_gelu(const float* __restrict__ u,
                                                     const float2* __restrict__ Kf,
                                                     ushort_t* __restrict__ g)
{
    __shared__ float2 SH[SH_SIZE];   // 139,264 B
    int h    = blockIdx.x;         // 512
    int pair = blockIdx.y;         // 4
    int b0   = pair * 2;
    int t    = threadIdx.x;
    const float* u0 = u + ((size_t)(b0 * 512 + h)) * 8192;
    const float* u1 = u0 + (size_t)512 * 8192;
    float2 x[16];
#pragma unroll
    for (int a = 0; a < 8; ++a) x[a] = make_float2(u0[a * 1024 + t], u1[a * 1024 + t]);
#pragma unroll
    for (int a = 8; a < 16; ++a) x[a] = make_float2(0.f, 0.f);
    fft_fwd(x, SH, t);
    const float2* kf = Kf + (size_t)blockIdx.x * 16384;
#pragma unroll
    for (int r = 0; r < 16; ++r) x[r] = cmulf(x[r], kf[r * 1024 + t]);
    fft_inv(x, SH, t);
    const float sc = 1.0f / 16384.0f;
    ushort_t* g0 = g + ((size_t)(b0 * 512 + blockIdx.x)) * 8192;
    ushort_t* g1 = g0 + (size_t)512 * 8192;
#pragma unroll
    for (int a = 0; a < 8; ++a) {
        int n = a * 1024 + t;
        g0[n] = f2bf(gelu_exact(x[a].x * sc));   // batch b0
        g1[n] = f2bf(gelu_exact(x[a].y * sc));   // batch b0+1
    }
}

// ---------------- k3: out[b,o,l] = sum_h Wb[o,h]*g[b,h,l] + bias[o] ---------
// B-operand staged h-major; transpose happens in the LDS fragment gather.
// BIDX layout: writes 16B-aligned contiguous + conflict-free; u16 fragment
// reads hit 32 distinct banks (8q + mi/2) -- conflict-free. See R5 header.
#define BIDX(k, l) ((k) * 144 + (((k) >> 3) & 3) * 16 + (l))

__global__ __launch_bounds__(256, 2) void gemm_out(const ushort_t* __restrict__ Wb,
                                                   const ushort_t* __restrict__ g,
                                                   const float* __restrict__ bias,
                                                   float* __restrict__ out)
{
    __shared__ __align__(16) ushort_t As[128 * 32];  // [o][k]
    __shared__ __align__(16) ushort_t Bs2[4640];     // BIDX-layout [k][l]

    int lt = blockIdx.x;   // 64 l-tiles
    int ot = blockIdx.y;   // 4 o-tiles
    int b  = blockIdx.z;   // 8
    int l0 = lt * 128, o0 = ot * 128;
    int t    = threadIdx.x;
    int wave = t >> 6, lid = t & 63;
    int wm = wave >> 1, wn = wave & 1;
    int q  = lid >> 4, mi = lid & 15;

    f32x4 acc[4][4];
#pragma unroll
    for (int i = 0; i < 4; ++i)
#pragma unroll
        for (int j = 0; j < 4; ++j)
            acc[i][j] = (f32x4){0.f, 0.f, 0.f, 0.f};

    const ushort_t* gb = g + (size_t)b * 512 * 8192;   // g[b][h][l]
    for (int it = 0; it < 16; ++it) {
        int k0 = it * 32;
        __syncthreads();
#pragma unroll
        for (int i = 0; i < 2; ++i) {
            int ch = t + (i << 8);           // 0..511 16B-chunks
            // A: Wb[o0+row][k0 + kc..kc+7]
            int arow = ch >> 2;
            int akc  = (ch & 3) << 3;
            uint4 va = *(const uint4*)(Wb + (size_t)(o0 + arow) * 512 + k0 + akc);
            *(uint4*)&As[arow * 32 + akc] = va;
            // B: g[b][k0+hr][l0 + lc*8..+7] -> Bs2[BIDX(hr, lc*8)]
            int hr = ch >> 4;                // 0..31
            int lc = ch & 15;                // 0..15
            uint4 vb = *(const uint4*)(gb + (size_t)(k0 + hr) * 8192 + l0 + (lc << 3));
            *(uint4*)&Bs2[BIDX(hr, lc << 3)] = vb;
        }
        __syncthreads();
        bf16x8 af[4], bfr[4];
#pragma unroll
        for (int ff = 0; ff < 4; ++ff) {
            af[ff] = *(const bf16x8*)&As[(wm * 64 + ff * 16 + mi) * 32 + q * 8];
            ushort8 bu;
#pragma unroll
            for (int j = 0; j < 8; ++j)
                bu[j] = Bs2[BIDX(q * 8 + j, wn * 64 + ff * 16 + mi)];
            bfr[ff] = __builtin_bit_cast(bf16x8, bu);
        }
#pragma unroll
        for (int i = 0; i < 4; ++i)
#pragma unroll
            for (int j = 0; j < 4; ++j)
                acc[i][j] = __builtin_amdgcn_mfma_f32_16x16x32_bf16(af[i], bfr[j], acc[i][j], 0, 0, 0);
    }

#pragma unroll
    for (int i = 0; i < 4; ++i) {
        int o_base = o0 + wm * 64 + i * 16 + q * 4;
#pragma unroll
        for (int j = 0; j < 4; ++j) {
            int l = l0 + wn * 64 + j * 16 + mi;
#pragma unroll
            for (int r = 0; r < 4; ++r) {
                int o = o_base + r;
                out[((size_t)b * 512 + o) * 8192 + l] = acc[i][j][r] + bias[o];
            }
        }
    }
}

// ----------------------------------------------------------------------------
extern "C" void kernel_launch(void* const* d_in, const int* in_sizes, int n_in,
                              void* d_out, int out_size, void* d_ws, size_t ws_size,
                              hipStream_t stream)
{
    (void)in_sizes; (void)n_in; (void)out_size; (void)ws_size;
    const float* u    = (const float*)d_in[0];   // (8,512,8192)
    const float* k    = (const float*)d_in[1];   // (1,512,8192)
    const float* D    = (const float*)d_in[2];   // (1,512)
    const float* W    = (const float*)d_in[3];   // (512,512)
    const float* bias = (const float*)d_in[4];   // (512,)
    float* out = (float*)d_out;

    char* ws = (char*)d_ws;
    float2*   Kf = (float2*)ws;                          // 512*16384*8 = 64 MB
    ushort_t* g  = (ushort_t*)(ws + 67108864);           // 64 MB
    ushort_t* Wb = (ushort_t*)(ws + 134217728);          // 512 KB

    wconv<<<1024, 256, 0, stream>>>(W, Wb, 512 * 512);
    kf_build<<<512, 1024, 0, stream>>>(k, D, Kf);
    conv_gelu<<<dim3(512, 4), 1024, 0, stream>>>(u, Kf, g);
    gemm_out<<<dim3(64, 4, 8), 256, 0, stream>>>(Wb, g, bias, out);
}

// Round 7
// 407.016 us; speedup vs baseline: 1.1921x; 1.0637x over previous
//
#include <hip/hip_runtime.h>

// ----------------------------------------------------------------------------
// S4 block: y = GELU( irfft(rfft(u,2L) * (rfft(k,2L) + D)) [:L] ) ; out = W@y + b
// B=8, C=1, H=512, L=8192, N=2L=16384
//
// FFT: four-step register-resident factorization 16384 = 16*16*16*4.
//   1024 threads, 16 complex points/thread in VGPRs. Full-wave exchanges
//   (R6): 16 regions x 1088 cplx = 139,264 B LDS, slot = region*1088 +
//   row*68 + CHI(col); exchange A / B'A' barriered, B/C/D'/C'B' intra-wave
//   with lgkmcnt(0) only. 2 barriers per conv_gelu.
//
// R7: PACKED-F32 complex arithmetic. R6 counters: conv_gelu = 205us with
//   VALUBusy 80% == the SCALAR VALU-issue floor (4G scalar adds / 256 CU /
//   64 lanes x 2cyc = 213us). The FFT is add-dominated; float2-as-struct
//   emits per-component v_add_f32. cplx = ext_vector_type(2) float with
//   vector +/- lets the backend emit v_pk_add_f32 (2 FLOP/lane/inst):
//   dft4 16 -> ~8-10 insts. +-i rotations via mi(y)=(y.y,-y.x) swizzle +
//   packed add/sub; cmul via broadcast pk_mul + pk_fma.
//   gemm/wconv byte-identical to R6 (one variable per round).
//
// __launch_bounds__(1024,1): do NOT force waves/EU (R1: forcing spills
//   catastrophically; R2: LDS/regfile pin 1 block/CU -- VGPR growth from
//   packing is free).
// ----------------------------------------------------------------------------

typedef unsigned short ushort_t;
typedef __bf16 bf16x8 __attribute__((ext_vector_type(8)));
typedef float  f32x4  __attribute__((ext_vector_type(4)));
typedef unsigned short ushort8 __attribute__((ext_vector_type(8)));
typedef float  cplx   __attribute__((ext_vector_type(2)));

#define TWO_PI 6.283185307179586f
#define LGKM() asm volatile("s_waitcnt lgkmcnt(0)" ::: "memory")
#define CHI(p) ((((p) & 0x3C)) | (((p) + ((p) >> 4)) & 3))

// -i * y  (the butterfly rotation); packed-add friendly
__device__ __forceinline__ cplx mi(cplx y) { return (cplx){y.y, -y.x}; }

// full complex multiply: a*b = a.x*b + a.y*(i*b)
__device__ __forceinline__ cplx cmul(cplx a, cplx b) {
    cplx ib = (cplx){-b.y, b.x};
    return a.x * b + a.y * ib;
}

// multiply by constant twiddle (wr, wi); INV conjugates the twiddle
template<bool INV>
__device__ __forceinline__ cplx cmulc(cplx a, float wr, float wi) {
    float i2 = INV ? -wi : wi;
    cplx ia = (cplx){-a.y, a.x};
    return wr * a + i2 * ia;
}

__device__ __forceinline__ ushort_t f2bf(float f) {
    unsigned int u = __float_as_uint(f);
    u = (u + 0x7fffu + ((u >> 16) & 1u)) >> 16;
    return (ushort_t)u;
}

__device__ __forceinline__ float gelu_exact(float x) {
    return 0.5f * x * (1.0f + erff(x * 0.70710678118654752f));
}

// ---------------- 4-point DFT, natural in/out (INV = conjugate kernel) ------
template<bool INV>
__device__ __forceinline__ void dft4(cplx& x0, cplx& x1, cplx& x2, cplx& x3) {
    cplx t0 = x0 + x2, t1 = x0 - x2;
    cplx t2 = x1 + x3, t3 = x1 - x3;
    x0 = t0 + t2;
    x2 = t0 - t2;
    cplx m = mi(t3);
    if (!INV) { x1 = t1 + m; x3 = t1 - m; }
    else      { x1 = t1 - m; x3 = t1 + m; }
}

#define C1_ 0.9238795325112867f
#define S1_ 0.3826834323650898f
#define R2_ 0.7071067811865476f

// ---------------- 16-point DFT, natural in/out ------------------------------
// four-step 16 = 4x4: n = 4a+b, k = c+4e.
// HZ: inputs r[8..15] are known-zero (skip half the inner butterflies).
template<bool INV, bool HZ>
__device__ __forceinline__ void dft16(cplx* r) {
#pragma unroll
    for (int b = 0; b < 4; ++b) {
        if (HZ) {
            cplx u = r[b], v = r[4 + b];
            r[b]     = u + v;
            r[8 + b] = u - v;
            cplx m = mi(v);
            if (!INV) { r[4 + b] = u + m; r[12 + b] = u - m; }
            else      { r[4 + b] = u - m; r[12 + b] = u + m; }
        } else {
            dft4<INV>(r[b], r[4 + b], r[8 + b], r[12 + b]);
        }
    }
    // twiddle r[4c+b] *= w16^{bc}
    r[5]  = cmulc<INV>(r[5],  C1_, -S1_);   // w^1
    r[6]  = cmulc<INV>(r[6],  R2_, -R2_);   // w^2
    r[7]  = cmulc<INV>(r[7],  S1_, -C1_);   // w^3
    r[9]  = cmulc<INV>(r[9],  R2_, -R2_);   // w^2
    r[10] = cmulc<INV>(r[10], 0.f, -1.f);   // w^4
    r[11] = cmulc<INV>(r[11], -R2_, -R2_);  // w^6
    r[13] = cmulc<INV>(r[13], S1_, -C1_);   // w^3
    r[14] = cmulc<INV>(r[14], -R2_, -R2_);  // w^6
    r[15] = cmulc<INV>(r[15], -C1_,  S1_);  // w^9
    cplx o[16];
#pragma unroll
    for (int c = 0; c < 4; ++c) {
        cplx a0 = r[4*c], a1 = r[4*c+1], a2 = r[4*c+2], a3 = r[4*c+3];
        dft4<INV>(a0, a1, a2, a3);
        o[c] = a0; o[c + 4] = a1; o[c + 8] = a2; o[c + 12] = a3;
    }
#pragma unroll
    for (int i = 0; i < 16; ++i) r[i] = o[i];
}

// apply w^k, w = e^{i*theta}, to x[1..15] (x[0] *= w^0)
__device__ __forceinline__ void twiddle_apply(cplx* x, float theta) {
    float s, c;
    __sincosf(theta, &s, &c);
    cplx w = (cplx){c, s}, wk = w;
#pragma unroll
    for (int k = 1; k < 16; ++k) { x[k] = cmul(x[k], wk); wk = cmul(wk, w); }
}

// ----------------------------------------------------------------------------
// Shared scratch: 16 regions x 1088 cplx = 17,408 cplx = 139,264 B.
//   slot(region,row,col) = region*1088 + row*68 + CHI(col), row in [0,16),
//   col in [0,64). 1 block/CU (accepted since R2).
// ----------------------------------------------------------------------------
#define SH_SIZE 17408
#define WREG 1088
#define ROWS 68

// ---------------- forward: regs(natural a-chunks) -> regs(sigma bins) -------
// thread t holds x[a] = in[a*1024 + t] (a=8..15 zero). Output: 16 sigma-bins.
__device__ __forceinline__ void fft_fwd(cplx* x, cplx* SH, int t) {
    const int w  = t >> 6;          // wave / k1
    const int d  = t & 63;
    const int kb = (t >> 2) & 15;
    const int f  = t & 3;
    const int xd = CHI(d);
    cplx* PW = SH + w * WREG;

    // phase A: DFT16 over a (half-zero) + twiddle w_N^t
    dft16<false, true>(x);
    twiddle_apply(x, -TWO_PI * (float)t * (1.0f / 16384.0f));

    // ---- exchange A (cross-wave): write [region r][row w][col d]; read own
#pragma unroll
    for (int r = 0; r < 16; ++r) SH[r * WREG + w * ROWS + xd] = x[r];
    __syncthreads();
#pragma unroll
    for (int c = 0; c < 16; ++c) x[c] = PW[c * ROWS + xd];

    // phase B: DFT16 over c + twiddle w_1024^d
    dft16<false, false>(x);
    twiddle_apply(x, -TWO_PI * (float)d * (1.0f / 1024.0f));

    // ---- exchange B (intra-wave): write [r][d], read [kb][4e+f]
#pragma unroll
    for (int r = 0; r < 16; ++r) PW[r * ROWS + xd] = x[r];
    LGKM();
#pragma unroll
    for (int e = 0; e < 16; ++e) x[e] = PW[kb * ROWS + CHI(e * 4 + f)];

    // phase C: DFT16 over e + twiddle w_64^f
    dft16<false, false>(x);
    twiddle_apply(x, -TWO_PI * (float)f * (1.0f / 64.0f));

    // ---- exchange C (intra-wave, row kb): write col r*4+f, read col f*16+q*4+ff
#pragma unroll
    for (int r = 0; r < 16; ++r) PW[kb * ROWS + CHI(r * 4 + f)] = x[r];
    LGKM();
#pragma unroll
    for (int q = 0; q < 4; ++q)
#pragma unroll
        for (int ff = 0; ff < 4; ++ff)
            x[q * 4 + ff] = PW[kb * ROWS + CHI(f * 16 + q * 4 + ff)];

    // phase D: DFT4 over ff
#pragma unroll
    for (int q = 0; q < 4; ++q) dft4<false>(x[4*q], x[4*q+1], x[4*q+2], x[4*q+3]);
}

// ---------------- inverse: exact mirror; output x[a] = 16384 * time[a*1024+t]
__device__ __forceinline__ void fft_inv(cplx* x, cplx* SH, int t) {
    const int w  = t >> 6;
    const int d  = t & 63;
    const int kb = (t >> 2) & 15;
    const int f  = t & 3;
    const int xd = CHI(d);
    cplx* PW = SH + w * WREG;

    // phase D'
#pragma unroll
    for (int q = 0; q < 4; ++q) dft4<true>(x[4*q], x[4*q+1], x[4*q+2], x[4*q+3]);

    // ---- exchange D' (mirror of C): write col f*16+q*4+ff, read col r*4+f
#pragma unroll
    for (int q = 0; q < 4; ++q)
#pragma unroll
        for (int ff = 0; ff < 4; ++ff)
            PW[kb * ROWS + CHI(f * 16 + q * 4 + ff)] = x[q * 4 + ff];
    LGKM();
#pragma unroll
    for (int r = 0; r < 16; ++r) x[r] = PW[kb * ROWS + CHI(r * 4 + f)];

    // phase C'
    twiddle_apply(x, TWO_PI * (float)f * (1.0f / 64.0f));
    dft16<true, false>(x);

    // ---- exchange C'B' (mirror of B): write [kb][4e+f], read [r][d]
#pragma unroll
    for (int e = 0; e < 16; ++e) PW[kb * ROWS + CHI(e * 4 + f)] = x[e];
    LGKM();
#pragma unroll
    for (int r = 0; r < 16; ++r) x[r] = PW[r * ROWS + xd];

    // phase B'
    twiddle_apply(x, TWO_PI * (float)d * (1.0f / 1024.0f));
    dft16<true, false>(x);

    // ---- exchange B'A' (mirror of A): write own [row c][col d]; read cross
#pragma unroll
    for (int c = 0; c < 16; ++c) PW[c * ROWS + xd] = x[c];
    __syncthreads();
#pragma unroll
    for (int r = 0; r < 16; ++r) x[r] = SH[r * WREG + w * ROWS + xd];

    // phase A'
    twiddle_apply(x, TWO_PI * (float)t * (1.0f / 16384.0f));
    dft16<true, false>(x);
}

// ---------------- k0: W fp32 -> bf16 ----------------------------------------
__global__ void wconv(const float* __restrict__ W, ushort_t* __restrict__ Wb, int n)
{
    int i = blockIdx.x * 256 + threadIdx.x;
    if (i < n) Wb[i] = f2bf(W[i]);
}

// ---------------- k1: Kf[h][sigma] = FFT(k[h]) + D[h] -----------------------
__global__ __launch_bounds__(1024, 1) void kf_build(const float* __restrict__ k,
                                                    const float* __restrict__ D,
                                                    cplx* __restrict__ Kf)
{
    __shared__ cplx SH[SH_SIZE];   // 139,264 B
    int h = blockIdx.x, t = threadIdx.x;
    const float* kr = k + (size_t)h * 8192;
    cplx x[16];
#pragma unroll
    for (int a = 0; a < 8; ++a) x[a] = (cplx){kr[a * 1024 + t], 0.f};
#pragma unroll
    for (int a = 8; a < 16; ++a) x[a] = (cplx){0.f, 0.f};
    fft_fwd(x, SH, t);
    float dh = D[h];
    cplx* o = Kf + (size_t)h * 16384;
#pragma unroll
    for (int r = 0; r < 16; ++r) {
        cplx z = x[r];
        z.x += dh;                       // FFT(D*delta) = D on every bin
        o[r * 1024 + t] = z;
    }
}

// ---------------- k2: conv + D-skip + GELU -> g bf16 ------------------------
__global__ __launch_bounds__(1024, 1) void conv_gelu(const float* __restrict__ u,
                                                     const cplx* __restrict__ Kf,
                                                     ushort_t* __restrict__ g)
{
    __shared__ cplx SH[SH_SIZE];   // 139,264 B
    int h    = blockIdx.x;         // 512
    int pair = blockIdx.y;         // 4
    int b0   = pair * 2;
    int t    = threadIdx.x;
    const float* u0 = u + ((size_t)(b0 * 512 + h)) * 8192;
    const float* u1 = u0 + (size_t)512 * 8192;
    cplx x[16];
#pragma unroll
    for (int a = 0; a < 8; ++a) x[a] = (cplx){u0[a * 1024 + t], u1[a * 1024 + t]};
#pragma unroll
    for (int a = 8; a < 16; ++a) x[a] = (cplx){0.f, 0.f};
    fft_fwd(x, SH, t);
    const cplx* kf = Kf + (size_t)blockIdx.x * 16384;
#pragma unroll
    for (int r = 0; r < 16; ++r) x[r] = cmul(x[r], kf[r * 1024 + t]);
    fft_inv(x, SH, t);
    const float sc = 1.0f / 16384.0f;
    ushort_t* g0 = g + ((size_t)(b0 * 512 + blockIdx.x)) * 8192;
    ushort_t* g1 = g0 + (size_t)512 * 8192;
#pragma unroll
    for (int a = 0; a < 8; ++a) {
        int n = a * 1024 + t;
        g0[n] = f2bf(gelu_exact(x[a].x * sc));   // batch b0
        g1[n] = f2bf(gelu_exact(x[a].y * sc));   // batch b0+1
    }
}

// ---------------- k3: out[b,o,l] = sum_h Wb[o,h]*g[b,h,l] + bias[o] ---------
// B-operand staged h-major; transpose happens in the LDS fragment gather.
// BIDX layout: writes 16B-aligned contiguous + conflict-free; u16 fragment
// reads hit 32 distinct banks (8q + mi/2) -- conflict-free. See R5 header.
#define BIDX(k, l) ((k) * 144 + (((k) >> 3) & 3) * 16 + (l))

__global__ __launch_bounds__(256, 2) void gemm_out(const ushort_t* __restrict__ Wb,
                                                   const ushort_t* __restrict__ g,
                                                   const float* __restrict__ bias,
                                                   float* __restrict__ out)
{
    __shared__ __align__(16) ushort_t As[128 * 32];  // [o][k]
    __shared__ __align__(16) ushort_t Bs2[4640];     // BIDX-layout [k][l]

    int lt = blockIdx.x;   // 64 l-tiles
    int ot = blockIdx.y;   // 4 o-tiles
    int b  = blockIdx.z;   // 8
    int l0 = lt * 128, o0 = ot * 128;
    int t    = threadIdx.x;
    int wave = t >> 6, lid = t & 63;
    int wm = wave >> 1, wn = wave & 1;
    int q  = lid >> 4, mi = lid & 15;

    f32x4 acc[4][4];
#pragma unroll
    for (int i = 0; i < 4; ++i)
#pragma unroll
        for (int j = 0; j < 4; ++j)
            acc[i][j] = (f32x4){0.f, 0.f, 0.f, 0.f};

    const ushort_t* gb = g + (size_t)b * 512 * 8192;   // g[b][h][l]
    for (int it = 0; it < 16; ++it) {
        int k0 = it * 32;
        __syncthreads();
#pragma unroll
        for (int i = 0; i < 2; ++i) {
            int ch = t + (i << 8);           // 0..511 16B-chunks
            // A: Wb[o0+row][k0 + kc..kc+7]
            int arow = ch >> 2;
            int akc  = (ch & 3) << 3;
            uint4 va = *(const uint4*)(Wb + (size_t)(o0 + arow) * 512 + k0 + akc);
            *(uint4*)&As[arow * 32 + akc] = va;
            // B: g[b][k0+hr][l0 + lc*8..+7] -> Bs2[BIDX(hr, lc*8)]
            int hr = ch >> 4;                // 0..31
            int lc = ch & 15;                // 0..15
            uint4 vb = *(const uint4*)(gb + (size_t)(k0 + hr) * 8192 + l0 + (lc << 3));
            *(uint4*)&Bs2[BIDX(hr, lc << 3)] = vb;
        }
        __syncthreads();
        bf16x8 af[4], bfr[4];
#pragma unroll
        for (int ff = 0; ff < 4; ++ff) {
            af[ff] = *(const bf16x8*)&As[(wm * 64 + ff * 16 + mi) * 32 + q * 8];
            ushort8 bu;
#pragma unroll
            for (int j = 0; j < 8; ++j)
                bu[j] = Bs2[BIDX(q * 8 + j, wn * 64 + ff * 16 + mi)];
            bfr[ff] = __builtin_bit_cast(bf16x8, bu);
        }
#pragma unroll
        for (int i = 0; i < 4; ++i)
#pragma unroll
            for (int j = 0; j < 4; ++j)
                acc[i][j] = __builtin_amdgcn_mfma_f32_16x16x32_bf16(af[i], bfr[j], acc[i][j], 0, 0, 0);
    }

#pragma unroll
    for (int i = 0; i < 4; ++i) {
        int o_base = o0 + wm * 64 + i * 16 + q * 4;
#pragma unroll
        for (int j = 0; j < 4; ++j) {
            int l = l0 + wn * 64 + j * 16 + mi;
#pragma unroll
            for (int r = 0; r < 4; ++r) {
                int o = o_base + r;
                out[((size_t)b * 512 + o) * 8192 + l] = acc[i][j][r] + bias[o];
            }
        }
    }
}

// ----------------------------------------------------------------------------
extern "C" void kernel_launch(void* const* d_in, const int* in_sizes, int n_in,
                              void* d_out, int out_size, void* d_ws, size_t ws_size,
                              hipStream_t stream)
{
    (void)in_sizes; (void)n_in; (void)out_size; (void)ws_size;
    const float* u    = (const float*)d_in[0];   // (8,512,8192)
    const float* k    = (const float*)d_in[1];   // (1,512,8192)
    const float* D    = (const float*)d_in[2];   // (1,512)
    const float* W    = (const float*)d_in[3];   // (512,512)
    const float* bias = (const float*)d_in[4];   // (512,)
    float* out = (float*)d_out;

    char* ws = (char*)d_ws;
    cplx*     Kf = (cplx*)ws;                            // 512*16384*8 = 64 MB
    ushort_t* g  = (ushort_t*)(ws + 67108864);           // 64 MB
    ushort_t* Wb = (ushort_t*)(ws + 134217728);          // 512 KB

    wconv<<<1024, 256, 0, stream>>>(W, Wb, 512 * 512);
    kf_build<<<512, 1024, 0, stream>>>(k, D, Kf);
    conv_gelu<<<dim3(512, 4), 1024, 0, stream>>>(u, Kf, g);
    gemm_out<<<dim3(64, 4, 8), 256, 0, stream>>>(Wb, g, bias, out);
}